// Round 3
// baseline (147.481 us; speedup 1.0000x reference)
//
#include <hip/hip_runtime.h>

// SparseMCFModel — flow depends only on demands/edge_row/edge_col (GAT/GRU dead).
//   V_1[v] = relu(d[v])/deg[v]
//   V_j[v] = (relu(d[v]) + sum_{e:col=v} V_{j-1}[row_e]) / deg[v],  j=2..10
//   out[e] = V_10[row_e]
//
// r17: two dispatches + one-node-per-thread iteration grid.
//  POST-MORTEM r15/r16: multi-level dataflow convoys (every wave depends on
//  ~every other wave per level; spin-poll per level ~7us > barrier ~2us).
//  Barriers win on this graph. So: make barriers + build cheaper instead.
//  - Dispatch 1 (128 blk): edge-parallel build. deg/fill via agent atomics,
//    pcsc/overflow via PLAIN stores (L2 write-back, coalesced at flush) —
//    kernel boundary provides global sync + cache flush/invalidate, the
//    standard HIP producer->consumer guarantee. No in-kernel barrier at all.
//  - Dispatch 2 (40 blk x 512 = 20480 thr): one node per thread. No roles,
//    no LDS. 9 rounds x {24 unconditional coherent gathers -> sum -> publish
//    -> gbar(40 arrivals)}. Unused er slots padded to index N_NODES whose V
//    is 0.0 (memset) -> +0.0f at tail positions, bitwise-neutral (all V>=+0).
//  - Level V2 computed directly from demands/deg (plain loads; formula
//    bitwise-validated in r15/r16 at absmax 0.0) — saves one publish round.
//  - Summation order per node unchanged vs r14/r15: slots 0..cnt-1 ascending.
// Soundness: cross-block mutable data within dispatch 2 only via agent-scope
// atomic ops; gbar as r14 (syncthreads drains vmcnt before arrival; watchdog
// keeps any anomaly diagnosable instead of hanging); 40 blocks trivially
// co-resident.

#define N_NODES 20000
#define N_EDGES 200000
#define NTHR 512
#define NBLK1 128
#define QPB 391                            // quads per build block (391*128=50048)
#define NBLK2 40                           // 40*512 = 20480 >= 20000 owners
#define CAP 24                             // padded in-edge slots per node
#define NQUAD 50000                        // N_EDGES/4 int4 quads
#define OFL_MAX 4096
#define NP1 (N_NODES + 1)                  // V arrays have a zero pad at [N_NODES]
#define SPIN_MAX 65536                     // watchdog

__device__ __forceinline__ float ld_coh(const float* p) {
    return __hip_atomic_load(p, __ATOMIC_RELAXED, __HIP_MEMORY_SCOPE_AGENT);
}
__device__ __forceinline__ void st_coh(float* p, float v) {
    __hip_atomic_store(p, v, __ATOMIC_RELAXED, __HIP_MEMORY_SCOPE_AGENT);
}

// Distributed-arrival barrier (r14 lineage), 40 arrivals, watchdog-bounded.
__device__ __forceinline__ void gbar(int* grp, int ord) {
    __syncthreads();
    if (threadIdx.x == 0) {
        __hip_atomic_fetch_add(&grp[(blockIdx.x & 7) * 32], 1,
                               __ATOMIC_RELAXED, __HIP_MEMORY_SCOPE_AGENT);
        const int target = NBLK2 * ord;
        for (int t = 0; t < SPIN_MAX; ++t) {
            int s = 0;
            #pragma unroll
            for (int g = 0; g < 8; ++g)
                s += __hip_atomic_load(&grp[g * 32], __ATOMIC_RELAXED,
                                       __HIP_MEMORY_SCOPE_AGENT);
            if (s >= target) break;
            __builtin_amdgcn_s_sleep(1);
        }
    }
    __syncthreads();
}

// ---- Dispatch 1: CSC build. Atomic counters, plain data stores. ----
__global__ __launch_bounds__(NTHR)
void build_k(const int* __restrict__ edge_row,
             const int* __restrict__ edge_col,
             int* __restrict__ deg,       // [N]      zeroed
             int* __restrict__ fill,      // [N]      zeroed
             int* __restrict__ pcsc,      // [N*CAP]  uninit
             int* __restrict__ ofl_cnt,   // [1]      zeroed
             int* __restrict__ ofl_v,     // [OFL_MAX]
             int* __restrict__ ofl_row)   // [OFL_MAX]
{
    const int m = blockIdx.x * QPB + threadIdx.x;
    if (threadIdx.x < QPB && m < NQUAD) {
        int4 r4 = ((const int4*)edge_row)[m];
        int4 c4 = ((const int4*)edge_col)[m];
        int rr[4] = {r4.x, r4.y, r4.z, r4.w};
        int cc[4] = {c4.x, c4.y, c4.z, c4.w};
        #pragma unroll
        for (int i = 0; i < 4; ++i) {
            __hip_atomic_fetch_add(&deg[rr[i]], 1,
                                   __ATOMIC_RELAXED, __HIP_MEMORY_SCOPE_AGENT);
            int idx = __hip_atomic_fetch_add(&fill[cc[i]], 1,
                                             __ATOMIC_RELAXED, __HIP_MEMORY_SCOPE_AGENT);
            if (idx < CAP) {
                pcsc[cc[i] * CAP + idx] = rr[i];           // plain, L2-coalesced
            } else {
                int o = __hip_atomic_fetch_add(ofl_cnt, 1,
                                               __ATOMIC_RELAXED, __HIP_MEMORY_SCOPE_AGENT);
                if (o < OFL_MAX) { ofl_v[o] = cc[i]; ofl_row[o] = rr[i]; }
            }
        }
    }
}

// ---- Dispatch 2: 9 flow rounds + output. One node per thread. ----
__global__ __launch_bounds__(NTHR)
void flow_k(const float* __restrict__ demands,
            const int* __restrict__ edge_row,
            float* __restrict__ out,
            const int* __restrict__ deg,
            const int* __restrict__ fill,
            const int* __restrict__ pcsc,
            const int* __restrict__ ofl_cnt,
            const int* __restrict__ ofl_v,
            const int* __restrict__ ofl_row,
            float* __restrict__ V0,       // [NP1] zeroed (pad V0[N]=0)
            float* __restrict__ V1b,      // [NP1] zeroed (pad V1b[N]=0)
            int* __restrict__ grp)        // [8*32] zeroed
{
    const int tx = threadIdx.x, bx = blockIdx.x;
    int bar = 0;

    const int v = bx * NTHR + tx;
    const bool own = (v < N_NODES);

    int   er[CAP];
    int   cnt = 0, ocnt = 0;
    float dposv = 0.0f, invd = 0.0f;

    if (own) {
        cnt = min(fill[v], CAP);                    // plain: prev dispatch
        const int4* pb = (const int4*)&pcsc[v * CAP];
        #pragma unroll
        for (int q = 0; q < 6; ++q) {
            int4 a = pb[q];
            er[q * 4 + 0] = a.x; er[q * 4 + 1] = a.y;
            er[q * 4 + 2] = a.z; er[q * 4 + 3] = a.w;
        }
        const float dv_f = (float)deg[v];
        dposv = fmaxf(demands[v], 0.0f);
        invd  = (deg[v] > 0) ? (1.0f / dv_f) : 0.0f;
        ocnt  = *ofl_cnt;                           // expected 0

        // -- V2 directly from inputs (V1[r] = relu(d[r])/deg[r] per slot) --
        float acc = dposv;
        #pragma unroll
        for (int s = 0; s < CAP; ++s)
            if (s < cnt)
                acc += fmaxf(demands[er[s]], 0.0f) * (1.0f / (float)deg[er[s]]);
        if (ocnt > 0) {
            for (int o = 0; o < ocnt && o < OFL_MAX; ++o)
                if (ofl_v[o] == v) {
                    int r = ofl_row[o];
                    acc += fmaxf(demands[r], 0.0f) * (1.0f / (float)deg[r]);
                }
        }
        st_coh(&V0[v], acc * invd);

        // pad unused slots -> index N_NODES (V*[N_NODES] == 0.0 from memset);
        // trailing +0.0f adds are bitwise-neutral (all V >= +0)
        #pragma unroll
        for (int s = 0; s < CAP; ++s)
            if (s >= cnt) er[s] = N_NODES;
    }
    gbar(grp, ++bar);

    // -- rounds j=3..10: branch-free 24-wide coherent gather, publish --
    #pragma unroll 1
    for (int j = 3; j <= 10; ++j) {
        const float* Vp = (j & 1) ? V0 : V1b;   // j odd reads even level in V0
        float*       Vn = (j & 1) ? V1b : V0;
        if (own) {
            float t[CAP];
            #pragma unroll
            for (int s = 0; s < CAP; ++s)
                t[s] = ld_coh(&Vp[er[s]]);      // unconditional, full MLP
            float acc = dposv;
            #pragma unroll
            for (int s = 0; s < CAP; ++s)       // deterministic slot order
                acc += t[s];
            if (ocnt > 0) {                     // exactness fallback, ~never
                for (int o = 0; o < ocnt && o < OFL_MAX; ++o)
                    if (ofl_v[o] == v) acc += ld_coh(&Vp[ofl_row[o]]);
            }
            st_coh(&Vn[v], acc * invd);
        }
        gbar(grp, ++bar);
    }

    // ---- out[e] = V_10[row_e] (j=10 wrote V0); float4 stores ----
    for (int qq = bx * NTHR + tx; qq < NQUAD; qq += NBLK2 * NTHR) {
        int4 r4 = ((const int4*)edge_row)[qq];
        float4 o4;
        o4.x = ld_coh(&V0[r4.x]);
        o4.y = ld_coh(&V0[r4.y]);
        o4.z = ld_coh(&V0[r4.z]);
        o4.w = ld_coh(&V0[r4.w]);
        ((float4*)out)[qq] = o4;
    }
}

extern "C" void kernel_launch(void* const* d_in, const int* in_sizes, int n_in,
                              void* d_out, int out_size, void* d_ws, size_t ws_size,
                              hipStream_t stream) {
    const float* demands  = (const float*)d_in[1];
    const int*   edge_row = (const int*)d_in[2];
    const int*   edge_col = (const int*)d_in[3];
    float*       out      = (float*)d_out;

    char* ws = (char*)d_ws;
    auto take = [&](size_t bytes) {
        void* p = (void*)ws;
        ws += (bytes + 127) & ~size_t(127);
        return p;
    };
    // ---- zero zone (one 0x00 memset) ----
    char* zone0 = ws;
    int*   deg     = (int*)  take(N_NODES * 4);
    int*   fill    = (int*)  take(N_NODES * 4);
    float* V0      = (float*)take(NP1 * 4);
    float* V1b     = (float*)take(NP1 * 4);
    int*   ofl_cnt = (int*)  take(4);
    int*   grp     = (int*)  take(8 * 32 * 4);
    size_t zone0_bytes = (size_t)(ws - zone0);
    // ---- uninitialized zone ----
    int*   pcsc    = (int*)  take((size_t)N_NODES * CAP * 4);
    int*   ofl_v   = (int*)  take(OFL_MAX * 4);
    int*   ofl_row = (int*)  take(OFL_MAX * 4);

    hipMemsetAsync(zone0, 0x00, zone0_bytes, stream);
    build_k<<<NBLK1, NTHR, 0, stream>>>(edge_row, edge_col,
                                        deg, fill, pcsc,
                                        ofl_cnt, ofl_v, ofl_row);
    flow_k<<<NBLK2, NTHR, 0, stream>>>(demands, edge_row, out,
                                       deg, fill, pcsc,
                                       ofl_cnt, ofl_v, ofl_row,
                                       V0, V1b, grp);
}